// Round 10
// baseline (59522.876 us; speedup 1.0000x reference)
//
#include <hip/hip_runtime.h>

// R10: R8's audited VALU BiLSTM with ONE change — output stored as FLOAT32.
// Theory: harness reads d_out as float32 (reference output dtype, per doc);
// R2-R9 stored bf16 u16 bits, which assemble into sane-magnitude junk floats
// (error ~0.996) regardless of compute correctness. R1's NaN, R0's 0.715 and
// the invisible R9 markers are all consistent with fp32 readback.
// B=32, T=512, D=H=512. fp32 in, fp32 out. One WG per (dir, batch):
// 64 wgs x 1024 threads, independent recurrences, no cross-WG sync, no ws.

#define Bv 32
#define Tv 512
#define Dv 512
#define Hv 512

__device__ __forceinline__ float sigmf_(float x) { return 1.0f / (1.0f + __expf(-x)); }
__device__ __forceinline__ float tanhf_(float x) { return 2.0f / (1.0f + __expf(-2.0f * x)) - 1.0f; }

__global__ __launch_bounds__(1024, 1) void bilstm_simple(
    const float* __restrict__ x,
    const int* __restrict__ lengths,
    const float* __restrict__ Wih_f, const float* __restrict__ Whh_f,
    const float* __restrict__ bih_f, const float* __restrict__ bhh_f,
    const float* __restrict__ Wih_b, const float* __restrict__ Whh_b,
    const float* __restrict__ bih_b, const float* __restrict__ bhh_b,
    float* __restrict__ out)   // [B][T][2H] float32
{
    __shared__ float xh[Dv + Hv];    // [0,512)=x_t, [512,1024)=h
    __shared__ float cst[Hv];        // cell state
    __shared__ float gates[4 * Hv];  // pre-activations (gate-major i,f,g,o)
    __shared__ float bias[4 * Hv];   // b_ih + b_hh

    const int tid  = threadIdx.x;
    const int wave = tid >> 6;
    const int lane = tid & 63;
    const int dir  = blockIdx.x >> 5;   // 0 fwd, 1 bwd
    const int b    = blockIdx.x & 31;

    const float* Wih = dir ? Wih_b : Wih_f;
    const float* Whh = dir ? Whh_b : Whh_f;
    const float* bih = dir ? bih_b : bih_f;
    const float* bhh = dir ? bhh_b : bhh_f;

    for (int i = tid; i < 4 * Hv; i += 1024) bias[i] = bih[i] + bhh[i];
    for (int i = tid; i < Hv; i += 1024) { xh[Dv + i] = 0.f; cst[i] = 0.f; }
    const int len = lengths[b];

    // lane k-slice: k in [lane*16, lane*16+16). Lanes 0..31 -> x part (W_ih),
    // lanes 32..63 -> h part (W_hh). Both W have 512 columns.
    const float* Wbase = (lane < 32) ? Wih : Whh;
    const int koff = (lane & 31) * 16;

    for (int s = 0; s < Tv; ++s) {
        const int t = dir ? (Tv - 1 - s) : s;

        __syncthreads();   // previous step's update complete
        for (int i = tid; i < Dv; i += 1024)
            xh[i] = x[((size_t)b * Tv + t) * Dv + i];
        __syncthreads();

        // Per-lane slice of [x_t | h]
        float4 xr0 = *(const float4*)(xh + lane * 16 + 0);
        float4 xr1 = *(const float4*)(xh + lane * 16 + 4);
        float4 xr2 = *(const float4*)(xh + lane * 16 + 8);
        float4 xr3 = *(const float4*)(xh + lane * 16 + 12);

        // Each wave computes 128 gate rows: gates[row] = W_row . [x|h]
        #pragma unroll 4
        for (int rr = 0; rr < 128; ++rr) {
            const int row = wave * 128 + rr;
            const float4* wr = (const float4*)(Wbase + (size_t)row * 512 + koff);
            const float4 w0 = wr[0], w1 = wr[1], w2 = wr[2], w3 = wr[3];
            float acc = w0.x * xr0.x + w0.y * xr0.y + w0.z * xr0.z + w0.w * xr0.w
                      + w1.x * xr1.x + w1.y * xr1.y + w1.z * xr1.z + w1.w * xr1.w
                      + w2.x * xr2.x + w2.y * xr2.y + w2.z * xr2.z + w2.w * xr2.w
                      + w3.x * xr3.x + w3.y * xr3.y + w3.z * xr3.z + w3.w * xr3.w;
            #pragma unroll
            for (int off = 32; off > 0; off >>= 1)
                acc += __shfl_xor(acc, off, 64);
            if (lane == 0) gates[row] = acc;
        }
        __syncthreads();

        // LSTM pointwise update + masked hold + FLOAT32 output store
        if (tid < Hv) {
            const int cc = tid;
            const float gi = sigmf_(gates[0 * Hv + cc] + bias[0 * Hv + cc]);
            const float gf = sigmf_(gates[1 * Hv + cc] + bias[1 * Hv + cc]);
            const float gg = tanhf_(gates[2 * Hv + cc] + bias[2 * Hv + cc]);
            const float go = sigmf_(gates[3 * Hv + cc] + bias[3 * Hv + cc]);
            const float cn = gf * cst[cc] + gi * gg;
            const float hn = go * tanhf_(cn);
            const bool v = (t < len);           // mask: lengths[b] > t
            const float hnew = v ? hn : xh[Dv + cc];
            cst[cc] = v ? cn : cst[cc];
            xh[Dv + cc] = hnew;
            out[((size_t)b * Tv + t) * (2 * Hv) + dir * Hv + cc] = hnew;
        }
    }
}

extern "C" void kernel_launch(void* const* d_in, const int* in_sizes, int n_in,
                              void* d_out, int out_size, void* d_ws, size_t ws_size,
                              hipStream_t stream) {
    (void)out_size; (void)d_ws; (void)ws_size;

    // Input-order guard via in_sizes (x = 8388608 elems is unambiguous).
    // Dict order (documented) expected: sizes [8388608, 32, 1M, 1M, 2K, 2K, ...].
    const void *x, *len_p, *Wihf, *Whhf, *bihf, *bhhf, *Wihb, *Whhb, *bihb, *bhhb;
    if (n_in == 10 && in_sizes[9] == 8388608 && in_sizes[8] == 32) {
        // alphabetical pytree order fallback
        Whhb = d_in[0]; Whhf = d_in[1]; Wihb = d_in[2]; Wihf = d_in[3];
        bhhb = d_in[4]; bhhf = d_in[5]; bihb = d_in[6]; bihf = d_in[7];
        len_p = d_in[8]; x = d_in[9];
    } else {
        // documented dict order
        x = d_in[0]; len_p = d_in[1];
        Wihf = d_in[2]; Whhf = d_in[3]; bihf = d_in[4]; bhhf = d_in[5];
        Wihb = d_in[6]; Whhb = d_in[7]; bihb = d_in[8]; bhhb = d_in[9];
    }

    bilstm_simple<<<dim3(64), dim3(1024), 0, stream>>>(
        (const float*)x, (const int*)len_p,
        (const float*)Wihf, (const float*)Whhf,
        (const float*)bihf, (const float*)bhhf,
        (const float*)Wihb, (const float*)Whhb,
        (const float*)bihb, (const float*)bhhb,
        (float*)d_out);
}